// Round 9
// baseline (58.422 us; speedup 1.0000x reference)
//
#include <hip/hip_runtime.h>

#define HW 2304          // 48*48
#define HW4 576          // HW/4 (float4 slots per batch row)
#define PART_STRIDE 2308 // 2304 A-partials + 1 sq, padded to mult of 4
#define S1_T 256         // stage-1 threads (4 waves; 8 blocks/CU possible)

typedef float __attribute__((ext_vector_type(4))) f32x4;

// Stage 1 (v9): final falsification of the ~3.9 TB/s read wall.
// (a) occupancy: 1152 blocks x 256 threads (4 waves, tiny VGPR) -> up to
//     8 blocks/CU = 100% wave occupancy WITH register accumulators
//     (R6's high-occ point was corrupted by LDS atomics in the hot loop).
//     Grid stride 1152*256 = 294912 = 512*576 ≡ 0 (mod 576), so each
//     thread's float4 hw-phase p = i0 % 576 is FIXED across iterations ->
//     4 register accumulators, no LDS in the loop.
// (b) __builtin_nontemporal_load: bypass L3 retention; if the mixed
//     L3/HBM service path is the cap, pure-HBM streaming re-balances.
// Each block's row is sparse (256 of 576 slots) -> zero row first, sync,
// then scatter each thread's f32x4 at slot p. Stage 2 is layout-agnostic
// (columnwise sum).
__global__ __launch_bounds__(S1_T, 8) void sc_stage1(
    const f32x4* __restrict__ out4, const f32x4* __restrict__ tgt4,
    float* __restrict__ part, int N4, int NB)
{
    int tid = threadIdx.x;
    int blk = blockIdx.x;
    int stride = NB * S1_T;            // ≡ 0 (mod 576) by construction
    int i0 = blk * S1_T + tid;
    int p  = i0 % HW4;                 // fixed hw phase for this thread

    float a0 = 0.f, a1 = 0.f, a2 = 0.f, a3 = 0.f, sq = 0.f;
    for (int i = i0; i < N4; i += stride) {
        f32x4 o = __builtin_nontemporal_load(&out4[i]);
        f32x4 t = __builtin_nontemporal_load(&tgt4[i]);
        float d;
        d = o[0] - t[0]; sq = fmaf(d, d, sq); a0 += fabsf(d);
        d = o[1] - t[1]; sq = fmaf(d, d, sq); a1 += fabsf(d);
        d = o[2] - t[2]; sq = fmaf(d, d, sq); a2 += fabsf(d);
        d = o[3] - t[3]; sq = fmaf(d, d, sq); a3 += fabsf(d);
    }

    // row writeback: zero all 577 f32x4 slots, sync, scatter accumulators
    float* pbase = part + (size_t)blk * PART_STRIDE;
    for (int k = tid; k < PART_STRIDE / 4; k += S1_T)
        ((f32x4*)pbase)[k] = (f32x4){0.f, 0.f, 0.f, 0.f};
    __syncthreads();
    ((f32x4*)pbase)[p] = (f32x4){a0, a1, a2, a3};   // hw = 4*p + c

    // block-reduce sq (4 waves)
    #pragma unroll
    for (int off = 32; off; off >>= 1) sq += __shfl_down(sq, off);
    __shared__ float wsum[4];
    if ((tid & 63) == 0) wsum[tid >> 6] = sq;
    __syncthreads();
    if (tid == 0)
        pbase[HW] = wsum[0] + wsum[1] + wsum[2] + wsum[3];
}

// Stage 2: 36 column blocks x 1024 threads = 64 hw-lanes x 16 row-groups.
// Each thread sums NB/16 rows; 16-way LDS reduce per hw. Block 36 reduces
// the per-block sq partials -> MSE into out[0] (plain store: idempotent
// across graph replays).
__global__ __launch_bounds__(1024) void sc_stage2(
    const float* __restrict__ part, float* __restrict__ A,
    float* __restrict__ out, int NB, int B, float invN)
{
    __shared__ float red[16][64];
    int lane = threadIdx.x & 63;
    int grp  = threadIdx.x >> 6;   // 0..15
    int blk  = blockIdx.x;
    if (blk < 36) {
        int hw = blk * 64 + lane;  // 64 consecutive floats per wave: coalesced
        float s = 0.f;
        for (int r = grp; r < NB; r += 16)
            s += part[(size_t)r * PART_STRIDE + hw];
        red[grp][lane] = s;
        __syncthreads();
        if (grp == 0) {
            float t = 0.f;
            #pragma unroll
            for (int g = 0; g < 16; ++g) t += red[g][lane];
            A[hw] = t / (float)B;
        }
    } else {
        float s = 0.f;
        for (int k = threadIdx.x; k < NB; k += 1024)
            s += part[(size_t)k * PART_STRIDE + HW];
        #pragma unroll
        for (int off = 32; off; off >>= 1) s += __shfl_down(s, off);
        if ((threadIdx.x & 63) == 0) red[0][grp] = s;
        __syncthreads();
        if (threadIdx.x == 0) {
            float t = 0.f;
            #pragma unroll
            for (int g = 0; g < 16; ++g) t += red[0][g];
            out[0] = t * invN;
        }
    }
}

// Stage 3: one block per (i,j): l1 = (A . |psu_ij|)/HW, then
// out += 0.5*mu*l1^2 (54 atomic adds; fp ordering noise ~1e-7 << threshold).
__global__ __launch_bounds__(256) void sc_stage3(
    const float* __restrict__ A, const float* __restrict__ psu,
    const float* __restrict__ mu, float* __restrict__ out)
{
    int j = blockIdx.x;
    int tid = threadIdx.x;
    const float* p = psu + (size_t)j * HW;
    float s = 0.f;
    for (int hw = tid; hw < HW; hw += 256) s += A[hw] * fabsf(p[hw]);
    #pragma unroll
    for (int off = 32; off; off >>= 1) s += __shfl_down(s, off);
    __shared__ float wsum[4];
    if ((tid & 63) == 0) wsum[tid >> 6] = s;
    __syncthreads();
    if (tid == 0) {
        float l1 = (wsum[0] + wsum[1] + wsum[2] + wsum[3]) * (1.0f / HW);
        float contrib = 0.5f * mu[j] * l1 * l1;   // GAMMA = 1
        atomicAdd(out, contrib);
    }
}

extern "C" void kernel_launch(void* const* d_in, const int* in_sizes, int n_in,
                              void* d_out, int out_size, void* d_ws, size_t ws_size,
                              hipStream_t stream)
{
    const float* outp = (const float*)d_in[0];
    const float* tgtp = (const float*)d_in[1];
    const float* psu  = (const float*)d_in[2];
    const float* mu   = (const float*)d_in[3];

    int B   = in_sizes[0] / HW;     // 8192
    int nij = in_sizes[3];          // 54
    int N4  = in_sizes[0] / 4;      // total float4 count (B*HW4)

    // 1152 blocks (4.5/CU, stride 294912 ≡ 0 mod 576); fall back to 576
    // (stride 147456 ≡ 0 mod 576) if the workspace can't hold 1152 rows.
    int NB = 1152;
    if (((size_t)NB * PART_STRIDE + HW) * sizeof(float) > ws_size)
        NB = 576;

    float* part = (float*)d_ws;
    float* A    = part + (size_t)NB * PART_STRIDE;
    float invN  = 1.0f / ((float)B * (float)HW);

    sc_stage1<<<NB, S1_T, 0, stream>>>((const f32x4*)outp, (const f32x4*)tgtp,
                                       part, N4, NB);
    sc_stage2<<<37, 1024, 0, stream>>>(part, A, (float*)d_out, NB, B, invN);
    sc_stage3<<<nij, 256, 0, stream>>>(A, psu, mu, (float*)d_out);
}

// Round 10
// 47.722 us; speedup vs baseline: 1.2242x; 1.2242x over previous
//
#include <hip/hip_runtime.h>

#define HW 2304          // 48*48
#define HW4 576          // HW/4 (float4 slots per batch row)
#define PART_STRIDE 2308 // 2304 A-partials + 1 sq, padded to mult of 4

typedef float __attribute__((ext_vector_type(4))) f32x4;

// Stage 1 (v10): the clean occupancy test. T=576 keeps per-thread phase
// = tid under grid-stride for ANY block count (stride = NB*576 ≡ 0 mod 576),
// so accumulators stay in 4 registers and the part row writeback is dense —
// identical structure to the 3.9TB/s R2/R8 kernels. Single variable changed:
// NB 512 -> 768 = exactly 3 blocks/CU x 9 waves = 27/32 waves (84% occ vs
// ~40% in all previous register-accumulator variants). Normal loads (R9
// showed nontemporal forfeits the L3-resident half: +15us). If this stays
// ~39us at 84% occ, the read path is service-rate-bound (~3.9 TB/s mixed
// L3/HBM) and stage 1 is at its roofline.
__global__ __launch_bounds__(576) void sc_stage1(
    const f32x4* __restrict__ out4, const f32x4* __restrict__ tgt4,
    float* __restrict__ part, int N4, int stride)
{
    int tid = threadIdx.x;
    int blk = blockIdx.x;
    int i0  = blk * 576 + tid;     // i0 mod 576 == tid -> phase fixed

    float a0 = 0.f, a1 = 0.f, a2 = 0.f, a3 = 0.f, sq = 0.f;
    for (int i = i0; i < N4; i += stride) {
        f32x4 o = out4[i];
        f32x4 t = tgt4[i];
        float d;
        d = o[0] - t[0]; sq = fmaf(d, d, sq); a0 += fabsf(d);
        d = o[1] - t[1]; sq = fmaf(d, d, sq); a1 += fabsf(d);
        d = o[2] - t[2]; sq = fmaf(d, d, sq); a2 += fabsf(d);
        d = o[3] - t[3]; sq = fmaf(d, d, sq); a3 += fabsf(d);
    }

    float* pbase = part + (size_t)blk * PART_STRIDE;
    ((f32x4*)pbase)[tid] = (f32x4){a0, a1, a2, a3};   // pbase[4*tid+c]

    // block-reduce sq (9 waves)
    #pragma unroll
    for (int off = 32; off; off >>= 1) sq += __shfl_down(sq, off);
    __shared__ float wsum[9];
    int wid = tid >> 6;
    if ((tid & 63) == 0) wsum[wid] = sq;
    __syncthreads();
    if (tid == 0) {
        float s = 0.f;
        #pragma unroll
        for (int w = 0; w < 9; ++w) s += wsum[w];
        pbase[HW] = s;
    }
}

// Stage 2: 36 column blocks x 1024 threads = 64 hw-lanes x 16 row-groups.
// Each thread sums NB/16 rows; 16-way LDS reduce per hw. Block 36 reduces
// the per-block sq partials -> MSE into out[0] (plain store: idempotent
// across graph replays). Proven ~3us.
__global__ __launch_bounds__(1024) void sc_stage2(
    const float* __restrict__ part, float* __restrict__ A,
    float* __restrict__ out, int NB, int B, float invN)
{
    __shared__ float red[16][64];
    int lane = threadIdx.x & 63;
    int grp  = threadIdx.x >> 6;   // 0..15
    int blk  = blockIdx.x;
    if (blk < 36) {
        int hw = blk * 64 + lane;  // 64 consecutive floats per wave: coalesced
        float s = 0.f;
        for (int r = grp; r < NB; r += 16)
            s += part[(size_t)r * PART_STRIDE + hw];
        red[grp][lane] = s;
        __syncthreads();
        if (grp == 0) {
            float t = 0.f;
            #pragma unroll
            for (int g = 0; g < 16; ++g) t += red[g][lane];
            A[hw] = t / (float)B;
        }
    } else {
        float s = 0.f;
        for (int k = threadIdx.x; k < NB; k += 1024)
            s += part[(size_t)k * PART_STRIDE + HW];
        #pragma unroll
        for (int off = 32; off; off >>= 1) s += __shfl_down(s, off);
        if ((threadIdx.x & 63) == 0) red[0][grp] = s;
        __syncthreads();
        if (threadIdx.x == 0) {
            float t = 0.f;
            #pragma unroll
            for (int g = 0; g < 16; ++g) t += red[0][g];
            out[0] = t * invN;
        }
    }
}

// Stage 3: one block per (i,j): l1 = (A . |psu_ij|)/HW, then
// out += 0.5*mu*l1^2 (54 atomic adds; fp ordering noise ~1e-7 << threshold).
__global__ __launch_bounds__(256) void sc_stage3(
    const float* __restrict__ A, const float* __restrict__ psu,
    const float* __restrict__ mu, float* __restrict__ out)
{
    int j = blockIdx.x;
    int tid = threadIdx.x;
    const float* p = psu + (size_t)j * HW;
    float s = 0.f;
    for (int hw = tid; hw < HW; hw += 256) s += A[hw] * fabsf(p[hw]);
    #pragma unroll
    for (int off = 32; off; off >>= 1) s += __shfl_down(s, off);
    __shared__ float wsum[4];
    if ((tid & 63) == 0) wsum[tid >> 6] = s;
    __syncthreads();
    if (tid == 0) {
        float l1 = (wsum[0] + wsum[1] + wsum[2] + wsum[3]) * (1.0f / HW);
        float contrib = 0.5f * mu[j] * l1 * l1;   // GAMMA = 1
        atomicAdd(out, contrib);
    }
}

extern "C" void kernel_launch(void* const* d_in, const int* in_sizes, int n_in,
                              void* d_out, int out_size, void* d_ws, size_t ws_size,
                              hipStream_t stream)
{
    const float* outp = (const float*)d_in[0];
    const float* tgtp = (const float*)d_in[1];
    const float* psu  = (const float*)d_in[2];
    const float* mu   = (const float*)d_in[3];

    int B   = in_sizes[0] / HW;     // 8192
    int nij = in_sizes[3];          // 54
    int N4  = in_sizes[0] / 4;      // total float4 count (B*HW4)

    // 768 blocks = exactly 3 blocks/CU on 256 CUs, 27/32 waves, no tail.
    int NB = 768;
    while (NB > 96 &&
           ((size_t)NB * PART_STRIDE + HW) * sizeof(float) > ws_size)
        NB >>= 1;

    float* part = (float*)d_ws;
    float* A    = part + (size_t)NB * PART_STRIDE;
    float invN  = 1.0f / ((float)B * (float)HW);

    sc_stage1<<<NB, 576, 0, stream>>>((const f32x4*)outp, (const f32x4*)tgtp,
                                      part, N4, NB * 576);
    sc_stage2<<<37, 1024, 0, stream>>>(part, A, (float*)d_out, NB, B, invN);
    sc_stage3<<<nij, 256, 0, stream>>>(A, psu, mu, (float*)d_out);
}